// Round 7
// baseline (2250.166 us; speedup 1.0000x reference)
//
#include <hip/hip_runtime.h>

// Problem constants (from reference)
constexpr int B_   = 4;
constexpr int N_   = 16384;
constexpr int NOUT = 1170;   // 16384 // 14
constexpr int D_   = 128;
constexpr int O_   = 256;

typedef float f32x2 __attribute__((ext_vector_type(2)));
typedef unsigned long long u64;

// DPP fmax step (validated R4-R6: absmax=0 with this chain).
template <int CTRL>
__device__ __forceinline__ float dpp_fmax(float x) {
  int yi = __builtin_amdgcn_update_dpp(__float_as_int(x), __float_as_int(x),
                                       CTRL, 0xF, 0xF, false);
  return fmaxf(x, __int_as_float(yi));
}

// ---------------- FPS kernel ----------------
// One block per batch, 512 threads x 32 points, consecutive ownership
// (thread t owns [t*32, t*32+32) -> lane order == index order at every
// reduce tier -> np first-max tie semantics).
//
// Distance math lives in four inline-asm blocks whose x/y/z operands are
// "+v" in-outs: the values are consumed AND redefined by opaque volatile
// asm every iteration, so the compiler can neither sink the initial loads
// into the loop nor re-derive coords from memory — they must stay resident
// (R1-R6 all silently re-fetched/spilled: VGPR_Count 48/88/92/56/96 vs 128
// needed; active-CU VALUBusy only ~62%).
// Exactness: v_pk_add_f32/v_pk_mul_f32 are per-half IEEE f32 add/mul
// (identical rounding to scalar); subtraction is x + (-lx) with the
// negation an exact sign flip; association (dx^2+dy^2)+dz^2 matches np.
constexpr int TPB_FPS = 512;
constexpr int PPT   = N_ / TPB_FPS;  // 32 points per thread
constexpr int NPAIR = PPT / 2;       // 16 f32x2 pairs
constexpr int NW    = TPB_FPS / 64;  // 8 waves

// 4 pairs (8 points) of exact squared distances per asm block.
// 21 operands: 4 "=&v" s, 2 "=&v" temps, 12 "+v" coords, 3 "v" neg-center.
#define DIST1(P)                                              \
  "v_pk_add_f32 %[tA], %[x" #P "], %[nlx]\n\t"                \
  "v_pk_mul_f32 %[s" #P "], %[tA], %[tA]\n\t"                 \
  "v_pk_add_f32 %[tA], %[y" #P "], %[nly]\n\t"                \
  "v_pk_mul_f32 %[tB], %[tA], %[tA]\n\t"                      \
  "v_pk_add_f32 %[s" #P "], %[s" #P "], %[tB]\n\t"            \
  "v_pk_add_f32 %[tA], %[z" #P "], %[nlz]\n\t"                \
  "v_pk_mul_f32 %[tB], %[tA], %[tA]\n\t"                      \
  "v_pk_add_f32 %[s" #P "], %[s" #P "], %[tB]\n\t"

#define DIST4(i0)                                                         \
  do {                                                                    \
    f32x2 tA, tB;                                                         \
    asm volatile(DIST1(0) DIST1(1) DIST1(2) DIST1(3)                      \
        : [s0] "=&v"(s[(i0) + 0]), [s1] "=&v"(s[(i0) + 1]),               \
          [s2] "=&v"(s[(i0) + 2]), [s3] "=&v"(s[(i0) + 3]),               \
          [tA] "=&v"(tA), [tB] "=&v"(tB),                                 \
          [x0] "+v"(x[(i0) + 0]), [x1] "+v"(x[(i0) + 1]),                 \
          [x2] "+v"(x[(i0) + 2]), [x3] "+v"(x[(i0) + 3]),                 \
          [y0] "+v"(y[(i0) + 0]), [y1] "+v"(y[(i0) + 1]),                 \
          [y2] "+v"(y[(i0) + 2]), [y3] "+v"(y[(i0) + 3]),                 \
          [z0] "+v"(z[(i0) + 0]), [z1] "+v"(z[(i0) + 1]),                 \
          [z2] "+v"(z[(i0) + 2]), [z3] "+v"(z[(i0) + 3])                  \
        : [nlx] "v"(nlx), [nly] "v"(nly), [nlz] "v"(nlz));                \
  } while (0)

__global__ __launch_bounds__(TPB_FPS, 2)  // min 2 waves/EU -> 256-VGPR budget
__attribute__((amdgpu_waves_per_eu(2, 2)))
void fps_kernel(const float* __restrict__ pcd_x,
                int* __restrict__ sel,        // [B, NOUT] (workspace)
                float* __restrict__ out_c) {  // query_c [B, NOUT, 3]
  const int b = blockIdx.x, t = threadIdx.x;
  const float* __restrict__ P = pcd_x + (size_t)b * N_ * 3;
  const int base = t * PPT;  // consecutive ownership
  const int lane = t & 63;

  f32x2 x[NPAIR], y[NPAIR], z[NPAIR], dm[NPAIR];
#pragma unroll
  for (int k = 0; k < NPAIR; ++k) {
    const int p0 = base + 2 * k;
    x[k]  = f32x2{P[p0 * 3 + 0], P[p0 * 3 + 3]};
    y[k]  = f32x2{P[p0 * 3 + 1], P[p0 * 3 + 4]};
    z[k]  = f32x2{P[p0 * 3 + 2], P[p0 * 3 + 5]};
    dm[k] = f32x2{1e10f, 1e10f};
  }

  __shared__ float2 s_pair[2][NW];  // {wave max, idx bits}, parity-buffered

  float lx = P[0], ly = P[1], lz = P[2];
  if (t == 0) {
    sel[b * NOUT + 0] = 0;
    out_c[((size_t)b * NOUT + 0) * 3 + 0] = lx;
    out_c[((size_t)b * NOUT + 0) * 3 + 1] = ly;
    out_c[((size_t)b * NOUT + 0) * 3 + 2] = lz;
  }

  for (int step = 1; step < NOUT; ++step) {
    const int par = step & 1;

    // exact negation (sign flip): x - lx == x + (-lx) bit-exactly in IEEE
    const float nx = __int_as_float(__float_as_int(lx) ^ 0x80000000);
    const float ny = __int_as_float(__float_as_int(ly) ^ 0x80000000);
    const float nz = __int_as_float(__float_as_int(lz) ^ 0x80000000);
    const f32x2 nlx = {nx, nx}, nly = {ny, ny}, nlz = {nz, nz};

    f32x2 s[NPAIR];
    DIST4(0);
    DIST4(4);
    DIST4(8);
    DIST4(12);

    // dm update + running max (exact: min/max pick one input's bits)
    float bv = -1.0f;
#pragma unroll
    for (int k = 0; k < NPAIR; ++k) {
      dm[k].x = fminf(dm[k].x, s[k].x);
      dm[k].y = fminf(dm[k].y, s[k].y);
      bv = fmaxf(bv, fmaxf(dm[k].x, dm[k].y));
    }

    // pin dm resident (loop-carried through opaque asm)
    asm volatile("" : "+v"(dm[0]), "+v"(dm[1]), "+v"(dm[2]), "+v"(dm[3]),
                      "+v"(dm[4]), "+v"(dm[5]), "+v"(dm[6]), "+v"(dm[7]),
                      "+v"(dm[8]), "+v"(dm[9]), "+v"(dm[10]), "+v"(dm[11]),
                      "+v"(dm[12]), "+v"(dm[13]), "+v"(dm[14]), "+v"(dm[15]));

    // in-wave DPP max (lane 63 holds it) -> broadcast
    float wm = bv;
    wm = dpp_fmax<0xB1>(wm);   // quad xor1
    wm = dpp_fmax<0x4E>(wm);   // quad xor2
    wm = dpp_fmax<0x141>(wm);  // row_half_mirror
    wm = dpp_fmax<0x140>(wm);  // row_mirror
    wm = dpp_fmax<0x142>(wm);  // row_bcast15
    wm = dpp_fmax<0x143>(wm);  // row_bcast31
    const float wmax =
        __int_as_float(__builtin_amdgcn_readlane(__float_as_int(wm), 63));

    // in-thread first-max index (descending scan: last write = smallest j)
    int bi = 0;
#pragma unroll
    for (int k = NPAIR - 1; k >= 0; --k) {
      if (dm[k].y == bv) bi = base + 2 * k + 1;
      if (dm[k].x == bv) bi = base + 2 * k;
    }

    // first achieving lane = smallest index range (consecutive ownership)
    const u64 mask = __ballot(bv == wmax);
    const int flane = __builtin_ctzll(mask);
    if (lane == flane) {
      float2 pr;
      pr.x = wmax;
      pr.y = __int_as_float(bi);
      s_pair[par][t >> 6] = pr;  // one ds_write_b64 per wave
    }
    __syncthreads();  // the only barrier per step

    // lane-parallel cross-wave reduce (validated R6): lane reads entry
    // (lane&7); 3 DPP steps -> max over all 8; first matching lane = winner.
    const float2 e = s_pair[par][lane & (NW - 1)];
    float gv = e.x;
    gv = dpp_fmax<0xB1>(gv);
    gv = dpp_fmax<0x4E>(gv);
    gv = dpp_fmax<0x141>(gv);
    const u64 m2 = __ballot(e.x == gv);
    const int ww = __builtin_ctzll(m2);  // winner wave id in [0,8)
    int ri = __builtin_amdgcn_readlane(__float_as_int(e.y), ww);

    // ri is SGPR-uniform -> scalar coord loads
    lx = P[ri * 3 + 0];
    ly = P[ri * 3 + 1];
    lz = P[ri * 3 + 2];
    if (t == 0) {
      sel[b * NOUT + step] = ri;
      out_c[((size_t)b * NOUT + step) * 3 + 0] = lx;
      out_c[((size_t)b * NOUT + step) * 3 + 1] = ly;
      out_c[((size_t)b * NOUT + step) * 3 + 2] = lz;
    }
  }
}

// ---------------- projection + gathers ----------------
constexpr int TPB_PROJ = 256;
constexpr int RPB = 4;

__global__ __launch_bounds__(TPB_PROJ)
void proj_kernel(const float* __restrict__ tgt,
                 const float* __restrict__ pcd_v,
                 const float* __restrict__ W,
                 const float* __restrict__ bias,
                 const int* __restrict__ sel,
                 float* __restrict__ out_f,    // [B*NOUT, 256]
                 float* __restrict__ out_v) {  // [B*NOUT, 9]
  const int t = threadIdx.x;
  const int row0 = blockIdx.x * RPB;
  __shared__ float sA[RPB * D_];
  __shared__ int   sIdx[RPB];
  if (t < RPB) {
    const int row = row0 + t;
    const int b = row / NOUT;
    sIdx[t] = b * N_ + sel[row];
  }
  __syncthreads();
#pragma unroll
  for (int l = 0; l < RPB * D_ / TPB_PROJ; ++l) {
    const int e = t + l * TPB_PROJ;
    const int r = e >> 7, k = e & (D_ - 1);
    sA[e] = tgt[(size_t)sIdx[r] * D_ + k];
  }
  __syncthreads();
  float acc0 = 0.f, acc1 = 0.f, acc2 = 0.f, acc3 = 0.f;
#pragma unroll 8
  for (int k = 0; k < D_; ++k) {
    const float w = W[k * O_ + t];
    acc0 = fmaf(sA[0 * D_ + k], w, acc0);
    acc1 = fmaf(sA[1 * D_ + k], w, acc1);
    acc2 = fmaf(sA[2 * D_ + k], w, acc2);
    acc3 = fmaf(sA[3 * D_ + k], w, acc3);
  }
  const float bb = bias[t];
  out_f[(size_t)(row0 + 0) * O_ + t] = acc0 + bb;
  out_f[(size_t)(row0 + 1) * O_ + t] = acc1 + bb;
  out_f[(size_t)(row0 + 2) * O_ + t] = acc2 + bb;
  out_f[(size_t)(row0 + 3) * O_ + t] = acc3 + bb;
  if (t < RPB * 9) {
    const int r = t / 9, e = t - r * 9;
    out_v[(size_t)(row0 + r) * 9 + e] = pcd_v[(size_t)sIdx[r] * 9 + e];
  }
}

extern "C" void kernel_launch(void* const* d_in, const int* in_sizes, int n_in,
                              void* d_out, int out_size, void* d_ws, size_t ws_size,
                              hipStream_t stream) {
  const float* tgt   = (const float*)d_in[0];  // [4,16384,128]
  const float* pcd_x = (const float*)d_in[1];  // [4,16384,3]
  const float* pcd_v = (const float*)d_in[2];  // [4,16384,3,3]
  const float* W     = (const float*)d_in[3];  // [128,256]
  const float* bias  = (const float*)d_in[4];  // [256]

  float* out   = (float*)d_out;
  float* out_f = out;                                   // [4,1170,256]
  float* out_c = out + (size_t)B_ * NOUT * O_;          // [4,1170,3]
  float* out_v = out_c + (size_t)B_ * NOUT * 3;         // [4,1170,3,3]

  int* sel = (int*)d_ws;  // [4,1170] int32

  hipLaunchKernelGGL(fps_kernel, dim3(B_), dim3(TPB_FPS), 0, stream,
                     pcd_x, sel, out_c);
  hipLaunchKernelGGL(proj_kernel, dim3(B_ * NOUT / RPB), dim3(TPB_PROJ), 0, stream,
                     tgt, pcd_v, W, bias, sel, out_f, out_v);
}

// Round 8
// 2125.948 us; speedup vs baseline: 1.0584x; 1.0584x over previous
//
#include <hip/hip_runtime.h>

// Problem constants (from reference)
constexpr int B_   = 4;
constexpr int N_   = 16384;
constexpr int NOUT = 1170;   // 16384 // 14
constexpr int D_   = 128;
constexpr int O_   = 256;

typedef float f32x2 __attribute__((ext_vector_type(2)));
typedef unsigned long long u64;

// DPP fmax step (validated R4-R7: absmax=0 with this chain).
template <int CTRL>
__device__ __forceinline__ float dpp_fmax(float x) {
  int yi = __builtin_amdgcn_update_dpp(__float_as_int(x), __float_as_int(x),
                                       CTRL, 0xF, 0xF, false);
  return fmaxf(x, __int_as_float(yi));
}
// DPP imin step (same dataflow as the validated fmax chain; min is
// commutative/idempotent so the merge pattern is isomorphic).
template <int CTRL>
__device__ __forceinline__ int dpp_imin(int x) {
  int y = __builtin_amdgcn_update_dpp(x, x, CTRL, 0xF, 0xF, false);
  return y < x ? y : x;
}

// ---------------- FPS kernel ----------------
// R1-R7 lesson: the RA caps this kernel at ~96 VGPRs, so any design needing
// 128+ resident regs silently re-fetches 192KB/step of coords from L2
// (= the observed ~1.4-2.0us/step, L2-BW-bound). Fix: xs,ys live in LDS
// (128KB, immune to the RA), zs+dm in regs (32 regs — under the cap).
//
// 1024 threads x 16 points. Thread t owns pairs {2t+j*2048, 2t+1+j*2048},
// j=0..7: ds_read_b64 at lane-stride 8B = 2-way bank alias = free (m136).
// Ownership is NOT lane-monotone, so both reduce tiers select the winner by
// explicit idx-min among value-achievers (exact np first-max semantics):
//   in-thread: descending-j scan, .y before .x  -> thread's min achieving idx
//   in-wave:   6-DPP fmax -> readlane(63); mask non-achievers to INT_MAX;
//              6-DPP imin -> readlane(63)
//   cross-wave: 16 {val,idx} pairs in LDS; 4-DPP fmax + 4-DPP imin, lane-
//              parallel (every lane reads entry lane&15).
// Winner's z is exported by its owner thread through an LDS slot between
// bar1 and bar2 (bar2(k) orders it before any reader; bar1(k+1) orders the
// next write after all readers) — no L2 load on the critical path.
constexpr int TPB_FPS = 1024;
constexpr int PPT   = 16;            // points per thread
constexpr int NPR   = 8;             // f32x2 pairs per thread
constexpr int NW    = TPB_FPS / 64;  // 16 waves
constexpr size_t LDS_BYTES = (size_t)2 * N_ * 4 + NW * 8 + 16;  // 131216

__global__ __launch_bounds__(TPB_FPS, 1)
void fps_kernel(const float* __restrict__ pcd_x,
                int* __restrict__ sel,        // [B, NOUT] (workspace)
                float* __restrict__ out_c) {  // query_c [B, NOUT, 3]
  extern __shared__ float smem[];
  float*  xs     = smem;                       // [16384] 64KB
  float*  ys     = smem + N_;                  // [16384] 64KB
  float2* s_pair = (float2*)(smem + 2 * N_);   // [16]
  float*  s_z    = (float*)(s_pair + NW);      // [1]

  const int b = blockIdx.x, t = threadIdx.x;
  const int lane = t & 63, w = t >> 6;
  const float* __restrict__ P = pcd_x + (size_t)b * N_ * 3;

  f32x2 zs[NPR], dm[NPR];
#pragma unroll
  for (int j = 0; j < NPR; ++j) {
    const int p0 = 2 * t + j * 2048;
    const float x0 = P[p0 * 3 + 0], y0 = P[p0 * 3 + 1], z0 = P[p0 * 3 + 2];
    const float x1 = P[p0 * 3 + 3], y1 = P[p0 * 3 + 4], z1 = P[p0 * 3 + 5];
    *reinterpret_cast<f32x2*>(&xs[p0]) = f32x2{x0, x1};  // ds_write_b64
    *reinterpret_cast<f32x2*>(&ys[p0]) = f32x2{y0, y1};
    zs[j] = f32x2{z0, z1};
    dm[j] = f32x2{1e10f, 1e10f};
  }
  __syncthreads();

  float lx = P[0], ly = P[1], lz = P[2];
  if (t == 0) {
    sel[b * NOUT + 0] = 0;
    out_c[((size_t)b * NOUT + 0) * 3 + 0] = lx;
    out_c[((size_t)b * NOUT + 0) * 3 + 1] = ly;
    out_c[((size_t)b * NOUT + 0) * 3 + 2] = lz;
  }

  for (int step = 1; step < NOUT; ++step) {
    // exact negation (sign flip): a - c == a + (-c) bit-exactly in IEEE
    const float nx = __int_as_float(__float_as_int(lx) ^ 0x80000000);
    const float ny = __int_as_float(__float_as_int(ly) ^ 0x80000000);
    const float nz = __int_as_float(__float_as_int(lz) ^ 0x80000000);
    const f32x2 nlx = {nx, nx}, nly = {ny, ny}, nlz = {nz, nz};

    f32x2 bvv = {-1.0f, -1.0f};
    {
#pragma clang fp contract(off)
#pragma unroll
      for (int j = 0; j < NPR; ++j) {
        const int p0 = 2 * t + j * 2048;
        const f32x2 xv = *reinterpret_cast<const f32x2*>(&xs[p0]);
        const f32x2 yv = *reinterpret_cast<const f32x2*>(&ys[p0]);
        // EXACT np order per component: ((dx*dx + dy*dy) + dz*dz), no FMA
        const f32x2 dx = xv + nlx;
        const f32x2 dy = yv + nly;
        const f32x2 dz = zs[j] + nlz;
        const f32x2 s  = (dx * dx + dy * dy) + dz * dz;
        dm[j] = __builtin_elementwise_min(dm[j], s);   // v_pk_min_f32
        bvv   = __builtin_elementwise_max(bvv, dm[j]); // v_pk_max_f32
      }
    }
    const float bv = fmaxf(bvv.x, bvv.y);

    // pin zs (read-only: sinkable) and dm resident across the iteration
    asm volatile("" : "+v"(zs[0]), "+v"(zs[1]), "+v"(zs[2]), "+v"(zs[3]),
                      "+v"(zs[4]), "+v"(zs[5]), "+v"(zs[6]), "+v"(zs[7]));
    asm volatile("" : "+v"(dm[0]), "+v"(dm[1]), "+v"(dm[2]), "+v"(dm[3]),
                      "+v"(dm[4]), "+v"(dm[5]), "+v"(dm[6]), "+v"(dm[7]));

    // wave value max (lane 63) -> broadcast
    float wm = bv;
    wm = dpp_fmax<0xB1>(wm);   // quad xor1
    wm = dpp_fmax<0x4E>(wm);   // quad xor2
    wm = dpp_fmax<0x141>(wm);  // row_half_mirror
    wm = dpp_fmax<0x140>(wm);  // row_mirror
    wm = dpp_fmax<0x142>(wm);  // row_bcast15
    wm = dpp_fmax<0x143>(wm);  // row_bcast31
    const float wmax =
        __int_as_float(__builtin_amdgcn_readlane(__float_as_int(wm), 63));

    // in-thread min achieving index (descending j, .y before .x)
    int bi = 0x7fffffff;
#pragma unroll
    for (int j = NPR - 1; j >= 0; --j) {
      if (dm[j].y == bv) bi = 2 * t + j * 2048 + 1;
      if (dm[j].x == bv) bi = 2 * t + j * 2048;
    }
    // in-wave min index among wave-max achievers
    int mi = (bv == wmax) ? bi : 0x7fffffff;
    mi = dpp_imin<0xB1>(mi);
    mi = dpp_imin<0x4E>(mi);
    mi = dpp_imin<0x141>(mi);
    mi = dpp_imin<0x140>(mi);
    mi = dpp_imin<0x142>(mi);
    mi = dpp_imin<0x143>(mi);
    const int widx = __builtin_amdgcn_readlane(mi, 63);

    if (lane == 0) s_pair[w] = make_float2(wmax, __int_as_float(widx));
    __syncthreads();  // bar1

    // cross-wave: every lane reads entry (lane&15); xor1,xor2,xor7,xor15
    // give every lane the full 16-entry reduction.
    const float2 e = s_pair[lane & (NW - 1)];
    float gv = e.x;
    gv = dpp_fmax<0xB1>(gv);
    gv = dpp_fmax<0x4E>(gv);
    gv = dpp_fmax<0x141>(gv);
    gv = dpp_fmax<0x140>(gv);
    int m2 = (e.x == gv) ? __float_as_int(e.y) : 0x7fffffff;
    m2 = dpp_imin<0xB1>(m2);
    m2 = dpp_imin<0x4E>(m2);
    m2 = dpp_imin<0x141>(m2);
    m2 = dpp_imin<0x140>(m2);
    const int ri = __builtin_amdgcn_readfirstlane(m2);

    // winner's owner exports z through LDS (safe: bar2(k) before readers,
    // bar1(k+1) before the next write)
    if (t == ((ri & 2047) >> 1)) {
      const int oj = ri >> 11, oh = ri & 1;
      s_z[0] = oh ? zs[oj].y : zs[oj].x;
    }
    __syncthreads();  // bar2

    lx = xs[ri];   // LDS broadcast
    ly = ys[ri];
    lz = s_z[0];
    if (t == 0) {
      sel[b * NOUT + step] = ri;
      out_c[((size_t)b * NOUT + step) * 3 + 0] = lx;
      out_c[((size_t)b * NOUT + step) * 3 + 1] = ly;
      out_c[((size_t)b * NOUT + step) * 3 + 2] = lz;
    }
  }
}

// ---------------- projection + gathers ----------------
constexpr int TPB_PROJ = 256;
constexpr int RPB = 4;

__global__ __launch_bounds__(TPB_PROJ)
void proj_kernel(const float* __restrict__ tgt,
                 const float* __restrict__ pcd_v,
                 const float* __restrict__ W,
                 const float* __restrict__ bias,
                 const int* __restrict__ sel,
                 float* __restrict__ out_f,    // [B*NOUT, 256]
                 float* __restrict__ out_v) {  // [B*NOUT, 9]
  const int t = threadIdx.x;
  const int row0 = blockIdx.x * RPB;
  __shared__ float sA[RPB * D_];
  __shared__ int   sIdx[RPB];
  if (t < RPB) {
    const int row = row0 + t;
    const int b = row / NOUT;
    sIdx[t] = b * N_ + sel[row];
  }
  __syncthreads();
#pragma unroll
  for (int l = 0; l < RPB * D_ / TPB_PROJ; ++l) {
    const int e = t + l * TPB_PROJ;
    const int r = e >> 7, k = e & (D_ - 1);
    sA[e] = tgt[(size_t)sIdx[r] * D_ + k];
  }
  __syncthreads();
  float acc0 = 0.f, acc1 = 0.f, acc2 = 0.f, acc3 = 0.f;
#pragma unroll 8
  for (int k = 0; k < D_; ++k) {
    const float w = W[k * O_ + t];
    acc0 = fmaf(sA[0 * D_ + k], w, acc0);
    acc1 = fmaf(sA[1 * D_ + k], w, acc1);
    acc2 = fmaf(sA[2 * D_ + k], w, acc2);
    acc3 = fmaf(sA[3 * D_ + k], w, acc3);
  }
  const float bb = bias[t];
  out_f[(size_t)(row0 + 0) * O_ + t] = acc0 + bb;
  out_f[(size_t)(row0 + 1) * O_ + t] = acc1 + bb;
  out_f[(size_t)(row0 + 2) * O_ + t] = acc2 + bb;
  out_f[(size_t)(row0 + 3) * O_ + t] = acc3 + bb;
  if (t < RPB * 9) {
    const int r = t / 9, e = t - r * 9;
    out_v[(size_t)(row0 + r) * 9 + e] = pcd_v[(size_t)sIdx[r] * 9 + e];
  }
}

extern "C" void kernel_launch(void* const* d_in, const int* in_sizes, int n_in,
                              void* d_out, int out_size, void* d_ws, size_t ws_size,
                              hipStream_t stream) {
  const float* tgt   = (const float*)d_in[0];  // [4,16384,128]
  const float* pcd_x = (const float*)d_in[1];  // [4,16384,3]
  const float* pcd_v = (const float*)d_in[2];  // [4,16384,3,3]
  const float* W     = (const float*)d_in[3];  // [128,256]
  const float* bias  = (const float*)d_in[4];  // [256]

  float* out   = (float*)d_out;
  float* out_f = out;                                   // [4,1170,256]
  float* out_c = out + (size_t)B_ * NOUT * O_;          // [4,1170,3]
  float* out_v = out_c + (size_t)B_ * NOUT * 3;         // [4,1170,3,3]

  int* sel = (int*)d_ws;  // [4,1170] int32

  hipLaunchKernelGGL(fps_kernel, dim3(B_), dim3(TPB_FPS), LDS_BYTES, stream,
                     pcd_x, sel, out_c);
  hipLaunchKernelGGL(proj_kernel, dim3(B_ * NOUT / RPB), dim3(TPB_PROJ), 0, stream,
                     tgt, pcd_v, W, bias, sel, out_f, out_v);
}

// Round 9
// 1975.363 us; speedup vs baseline: 1.1391x; 1.0762x over previous
//
#include <hip/hip_runtime.h>

// Problem constants (from reference)
constexpr int B_   = 4;
constexpr int N_   = 16384;
constexpr int NOUT = 1170;   // 16384 // 14
constexpr int D_   = 128;
constexpr int O_   = 256;

typedef float f32x2 __attribute__((ext_vector_type(2)));
typedef unsigned long long u64;

// DPP fmax step (validated R4-R8: absmax=0 with this chain).
template <int CTRL>
__device__ __forceinline__ float dpp_fmax(float x) {
  int yi = __builtin_amdgcn_update_dpp(__float_as_int(x), __float_as_int(x),
                                       CTRL, 0xF, 0xF, false);
  return fmaxf(x, __int_as_float(yi));
}

// ---------------- FPS kernel ----------------
// R8 post-mortem: VALU-issue-bound (active-CU VALUBusy ~81%). R9 cuts the
// issued-instruction count in the reduce tail:
//  * LDS layout xs2[8][1024]/ys2[8][1024] f32x2 -> thread t owns points
//    [16t,16t+16) (MONOTONE in (wave,lane)), pair h at [h][t]: lane-stride
//    8B (2-way alias = free, m136), ds offsets fold to h*8192.
//  * monotone ownership -> first-achieving lane/wave == min index, so
//    ballot+ctz replaces the 6-DPP imin chain, and the 32-instr in-thread
//    rescan runs ONLY on the winning lane of the winning wave (other waves
//    skip via execz).
//  * winner lane publishes {x,y,z,idx} as one float4 (z from its own reg,
//    x/y re-read from LDS) -> no separate z-export round-trip; still 2
//    barriers/step; sel/out_c stores move off the critical path.
// Exactness: pk add/mul are per-half IEEE f32 (contract off), subtraction
// as +(-c) sign-flip, association ((dx2+dy2)+dz2) = np order; min-index
// tie-break at every tier == np first-max. dm/zs pinned via empty asm
// (R8-validated).
constexpr int TPB_FPS = 1024;
constexpr int NPR   = 8;             // f32x2 pairs per thread (16 points)
constexpr int NW    = TPB_FPS / 64;  // 16 waves
constexpr size_t LDS_BYTES = (size_t)2 * N_ * 4 + NW * 4 + 16;  // 131152

__global__ __launch_bounds__(TPB_FPS, 1)
void fps_kernel(const float* __restrict__ pcd_x,
                int* __restrict__ sel,        // [B, NOUT] (workspace)
                float* __restrict__ out_c) {  // query_c [B, NOUT, 3]
  extern __shared__ char smem_raw[];
  f32x2*  xs2   = (f32x2*)smem_raw;            // [8][1024] 64KB
  f32x2*  ys2   = xs2 + 8 * 1024;              // [8][1024] 64KB
  float*  s_val = (float*)(ys2 + 8 * 1024);    // [16]
  float4* s_res = (float4*)(s_val + NW);       // [1] {x,y,z,idx}

  const int b = blockIdx.x, t = threadIdx.x;
  const int lane = t & 63, w = t >> 6;
  const float* __restrict__ P = pcd_x + (size_t)b * N_ * 3;

  f32x2 zs[NPR], dm[NPR];
#pragma unroll
  for (int h = 0; h < NPR; ++h) {
    const int p0 = 16 * t + 2 * h;
    xs2[h * 1024 + t] = f32x2{P[p0 * 3 + 0], P[p0 * 3 + 3]};
    ys2[h * 1024 + t] = f32x2{P[p0 * 3 + 1], P[p0 * 3 + 4]};
    zs[h] = f32x2{P[p0 * 3 + 2], P[p0 * 3 + 5]};
    dm[h] = f32x2{1e10f, 1e10f};
  }
  __syncthreads();

  float lx = P[0], ly = P[1], lz = P[2];
  if (t == 0) {
    sel[b * NOUT + 0] = 0;
    out_c[((size_t)b * NOUT + 0) * 3 + 0] = lx;
    out_c[((size_t)b * NOUT + 0) * 3 + 1] = ly;
    out_c[((size_t)b * NOUT + 0) * 3 + 2] = lz;
  }

  for (int step = 1; step < NOUT; ++step) {
    // exact negation (sign flip): a - c == a + (-c) bit-exactly in IEEE
    const float nx = __int_as_float(__float_as_int(lx) ^ 0x80000000);
    const float ny = __int_as_float(__float_as_int(ly) ^ 0x80000000);
    const float nz = __int_as_float(__float_as_int(lz) ^ 0x80000000);
    const f32x2 nlx = {nx, nx}, nly = {ny, ny}, nlz = {nz, nz};

    f32x2 bvv = {-1.0f, -1.0f};
    {
#pragma clang fp contract(off)
#pragma unroll
      for (int h = 0; h < NPR; ++h) {
        const f32x2 xv = xs2[h * 1024 + t];   // ds_read_b64 offset:h*8192
        const f32x2 yv = ys2[h * 1024 + t];
        // EXACT np order per component: ((dx*dx + dy*dy) + dz*dz), no FMA
        const f32x2 dx = xv + nlx;
        const f32x2 dy = yv + nly;
        const f32x2 dz = zs[h] + nlz;
        const f32x2 s  = (dx * dx + dy * dy) + dz * dz;
        dm[h] = __builtin_elementwise_min(dm[h], s);
        bvv   = __builtin_elementwise_max(bvv, dm[h]);
      }
    }
    const float bv = fmaxf(bvv.x, bvv.y);

    // pin zs/dm resident across the iteration (R8-validated)
    asm volatile("" : "+v"(zs[0]), "+v"(zs[1]), "+v"(zs[2]), "+v"(zs[3]),
                      "+v"(zs[4]), "+v"(zs[5]), "+v"(zs[6]), "+v"(zs[7]));
    asm volatile("" : "+v"(dm[0]), "+v"(dm[1]), "+v"(dm[2]), "+v"(dm[3]),
                      "+v"(dm[4]), "+v"(dm[5]), "+v"(dm[6]), "+v"(dm[7]));

    // wave value max (6 DPP) -> lane0 publishes
    float wm = bv;
    wm = dpp_fmax<0xB1>(wm);   // quad xor1
    wm = dpp_fmax<0x4E>(wm);   // quad xor2
    wm = dpp_fmax<0x141>(wm);  // row_half_mirror
    wm = dpp_fmax<0x140>(wm);  // row_mirror
    wm = dpp_fmax<0x142>(wm);  // row_bcast15
    wm = dpp_fmax<0x143>(wm);  // row_bcast31
    const float wmax =
        __int_as_float(__builtin_amdgcn_readlane(__float_as_int(wm), 63));
    if (lane == 0) s_val[w] = wmax;
    __syncthreads();  // bar1

    // cross-wave value reduce: all lanes, 16 entries, 4 DPP (validated R8)
    const float e = s_val[lane & (NW - 1)];
    float gv = e;
    gv = dpp_fmax<0xB1>(gv);
    gv = dpp_fmax<0x4E>(gv);
    gv = dpp_fmax<0x141>(gv);
    gv = dpp_fmax<0x140>(gv);  // gv = block max (all lanes)

    // first wave achieving gv (lanes 0..15 carry wave w's max)
    const u64 wwm = __ballot((lane < NW) && (e == gv));
    const int ww = __builtin_ctzll(wwm);  // winner wave id (uniform)

    // winning wave only: first achieving lane rescans + publishes
    if (w == ww && bv == gv) {
      const u64 am = __ballot(true);  // achiever lanes (exec mask)
      if (lane == __builtin_ctzll(am)) {
        int bi = 0;
#pragma unroll
        for (int h = NPR - 1; h >= 0; --h) {  // descending: last write = min
          if (dm[h].y == bv) bi = 16 * t + 2 * h + 1;
          if (dm[h].x == bv) bi = 16 * t + 2 * h;
        }
        const int loc = bi & 15, hh = loc >> 1, hf = loc & 1;
        const f32x2 xv = xs2[hh * 1024 + t];
        const f32x2 yv = ys2[hh * 1024 + t];
        const float wx = hf ? xv.y : xv.x;
        const float wy = hf ? yv.y : yv.x;
        const float wz = hf ? zs[hh].y : zs[hh].x;
        s_res[0] = make_float4(wx, wy, wz, __int_as_float(bi));
        sel[b * NOUT + step] = bi;                       // off critical path
        out_c[((size_t)b * NOUT + step) * 3 + 0] = wx;
        out_c[((size_t)b * NOUT + step) * 3 + 1] = wy;
        out_c[((size_t)b * NOUT + step) * 3 + 2] = wz;
      }
    }
    __syncthreads();  // bar2

    const float4 r = s_res[0];  // same-address broadcast
    lx = r.x; ly = r.y; lz = r.z;
  }
}

// ---------------- projection + gathers ----------------
constexpr int TPB_PROJ = 256;
constexpr int RPB = 4;

__global__ __launch_bounds__(TPB_PROJ)
void proj_kernel(const float* __restrict__ tgt,
                 const float* __restrict__ pcd_v,
                 const float* __restrict__ W,
                 const float* __restrict__ bias,
                 const int* __restrict__ sel,
                 float* __restrict__ out_f,    // [B*NOUT, 256]
                 float* __restrict__ out_v) {  // [B*NOUT, 9]
  const int t = threadIdx.x;
  const int row0 = blockIdx.x * RPB;
  __shared__ float sA[RPB * D_];
  __shared__ int   sIdx[RPB];
  if (t < RPB) {
    const int row = row0 + t;
    const int b = row / NOUT;
    sIdx[t] = b * N_ + sel[row];
  }
  __syncthreads();
#pragma unroll
  for (int l = 0; l < RPB * D_ / TPB_PROJ; ++l) {
    const int e = t + l * TPB_PROJ;
    const int r = e >> 7, k = e & (D_ - 1);
    sA[e] = tgt[(size_t)sIdx[r] * D_ + k];
  }
  __syncthreads();
  float acc0 = 0.f, acc1 = 0.f, acc2 = 0.f, acc3 = 0.f;
#pragma unroll 8
  for (int k = 0; k < D_; ++k) {
    const float w = W[k * O_ + t];
    acc0 = fmaf(sA[0 * D_ + k], w, acc0);
    acc1 = fmaf(sA[1 * D_ + k], w, acc1);
    acc2 = fmaf(sA[2 * D_ + k], w, acc2);
    acc3 = fmaf(sA[3 * D_ + k], w, acc3);
  }
  const float bb = bias[t];
  out_f[(size_t)(row0 + 0) * O_ + t] = acc0 + bb;
  out_f[(size_t)(row0 + 1) * O_ + t] = acc1 + bb;
  out_f[(size_t)(row0 + 2) * O_ + t] = acc2 + bb;
  out_f[(size_t)(row0 + 3) * O_ + t] = acc3 + bb;
  if (t < RPB * 9) {
    const int r = t / 9, e = t - r * 9;
    out_v[(size_t)(row0 + r) * 9 + e] = pcd_v[(size_t)sIdx[r] * 9 + e];
  }
}

extern "C" void kernel_launch(void* const* d_in, const int* in_sizes, int n_in,
                              void* d_out, int out_size, void* d_ws, size_t ws_size,
                              hipStream_t stream) {
  const float* tgt   = (const float*)d_in[0];  // [4,16384,128]
  const float* pcd_x = (const float*)d_in[1];  // [4,16384,3]
  const float* pcd_v = (const float*)d_in[2];  // [4,16384,3,3]
  const float* W     = (const float*)d_in[3];  // [128,256]
  const float* bias  = (const float*)d_in[4];  // [256]

  float* out   = (float*)d_out;
  float* out_f = out;                                   // [4,1170,256]
  float* out_c = out + (size_t)B_ * NOUT * O_;          // [4,1170,3]
  float* out_v = out_c + (size_t)B_ * NOUT * 3;         // [4,1170,3,3]

  int* sel = (int*)d_ws;  // [4,1170] int32

  hipLaunchKernelGGL(fps_kernel, dim3(B_), dim3(TPB_FPS), LDS_BYTES, stream,
                     pcd_x, sel, out_c);
  hipLaunchKernelGGL(proj_kernel, dim3(B_ * NOUT / RPB), dim3(TPB_PROJ), 0, stream,
                     tgt, pcd_v, W, bias, sel, out_f, out_v);
}